// Round 6
// baseline (1454.966 us; speedup 1.0000x reference)
//
#include <hip/hip_runtime.h>

// Sparse 3x3x3 conv — direct-probe + dense cell-ordered features, dual-row waves,
// BRANCHLESS padded record loop (this round).
//
// Out set == in_pos + {-2,-1,0}^3, so for out row q and tap d in {0,1,2}^3 the
// contributing input cell is out_pos[q] + d.  Inputs are compacted into a
// DENSE, CELL-SORTED feature array (featd) via an occupancy prefix-scan, so
// the sorted out rows probe monotonically increasing dense ids -> L2/L1 hits.
// W is staged in LDS as f16 in [k][chunk][lane] layout (lane-linear b128 reads,
// no bank conflicts) with a 28th ALL-ZERO tap: record slots past a row's count
// are padded with dummy records (n=0, k=27) so the record loop has NO inner
// branches -> compiler interleaves both rows' feat loads ahead of both FMA
// blocks (2 independent chains/wave; round-5's conditional bodies serialized).
//
// Pipeline: memset itable; claim; count/scan/assign; copy; dup; conv.
// Workspace: itable 8MB | dtable 8MB | ownerof 600KB | scan arrays | featd 19.2MB

#define CELLS (1 << 21)
#define DUMMY_REC (27 << 18)          // n=0, k=27 (zero-weight tap)

typedef _Float16 half8 __attribute__((ext_vector_type(8)));

__global__ void claim_k(const int* __restrict__ ipos, int* __restrict__ itable, int N) {
    int n = blockIdx.x * blockDim.x + threadIdx.x;
    if (n >= N) return;
    int x = ipos[3 * n], y = ipos[3 * n + 1], z = ipos[3 * n + 2];
    atomicCAS(&itable[(x << 14) | (y << 7) | z], -1, n);
}

// One thread per cell: per-block occupancy count (2048 blocks x 1024 cells).
__global__ void count_k(const int* __restrict__ itable, int* __restrict__ blockcnt) {
    __shared__ int wsum[16];
    int cell = blockIdx.x * 1024 + threadIdx.x;
    unsigned long long m = __ballot(itable[cell] >= 0);
    int w = threadIdx.x >> 6;
    if ((threadIdx.x & 63) == 0) wsum[w] = __popcll(m);
    __syncthreads();
    if (threadIdx.x == 0) {
        int s = 0;
        for (int i = 0; i < 16; ++i) s += wsum[i];
        blockcnt[blockIdx.x] = s;
    }
}

// Single-block exclusive scan of 2048 block counts (2 per thread).
__global__ void scan_k(const int* __restrict__ blockcnt, int* __restrict__ blockbase,
                       int* __restrict__ totalbuf) {
    __shared__ int sc[1024];
    int t = threadIdx.x;
    int c0 = blockcnt[2 * t], c1 = blockcnt[2 * t + 1];
    int s = c0 + c1;
    sc[t] = s;
    __syncthreads();
    for (int off = 1; off < 1024; off <<= 1) {
        int v = (t >= off) ? sc[t - off] : 0;
        __syncthreads();
        sc[t] += v;
        __syncthreads();
    }
    int excl = sc[t] - s;
    blockbase[2 * t] = excl;
    blockbase[2 * t + 1] = excl + c0;
    if (t == 1023) totalbuf[0] = sc[t];
}

// Assign dense ids in cell order; dtable[cell] = dense or -1; ownerof[dense]=owner.
__global__ void assign_k(const int* __restrict__ itable, const int* __restrict__ blockbase,
                         int* __restrict__ dtable, int* __restrict__ ownerof) {
    __shared__ int wsum[16];
    int cell = blockIdx.x * 1024 + threadIdx.x;
    int owner = itable[cell];
    bool occ = owner >= 0;
    unsigned long long m = __ballot(occ);
    int lane = threadIdx.x & 63, w = threadIdx.x >> 6;
    if (lane == 0) wsum[w] = __popcll(m);
    __syncthreads();
    int woff = 0;
    for (int i = 0; i < w; ++i) woff += wsum[i];
    int dense = blockbase[blockIdx.x] + woff + __popcll(m & ((1ull << lane) - 1));
    dtable[cell] = occ ? dense : -1;
    if (occ) ownerof[dense] = owner;
}

// featd[dense] = feat[owner]  (32 threads per row, coalesced)
__global__ void copy_k(const int* __restrict__ ownerof, const float* __restrict__ feat,
                       float* __restrict__ featd, const int* __restrict__ totalbuf, int N) {
    int gid = blockIdx.x * blockDim.x + threadIdx.x;
    int d = gid >> 5;
    if (d >= totalbuf[0]) return;
    featd[gid] = feat[(ownerof[d] << 5) + (gid & 31)];
}

// Duplicate-position rows add into the owner's dense row (exact dedup).
__global__ void dup_k(const int* __restrict__ ipos, const int* __restrict__ itable,
                      const int* __restrict__ dtable, const float* __restrict__ feat,
                      float* __restrict__ featd, int N) {
    int gid = blockIdx.x * blockDim.x + threadIdx.x;
    int n = gid >> 5;
    if (n >= N) return;
    int x = ipos[3 * n], y = ipos[3 * n + 1], z = ipos[3 * n + 2];
    int cell = (x << 14) | (y << 7) | z;
    if (itable[cell] == n) return;
    int c = gid & 31;
    atomicAdd(&featd[(dtable[cell] << 5) + c], feat[(n << 5) + c]);
}

// 16 mixed FMAs for one record of row-list sj into accumulators A0..A3.
#define RECBODY(sj, r, A0, A1, A2, A3)                                          \
    {                                                                           \
        int rec = sj[r];                                                        \
        int n = rec & 0x3FFFF, k = rec >> 18;                                   \
        const float4* fr = (const float4*)(featd + (n << 5)) + (ch << 2);       \
        float4 x0 = fr[0], x1 = fr[1], x2 = fr[2], x3 = fr[3];                  \
        half8 w0 = wp[(k << 7) + lane];                                         \
        half8 w1 = wp[(k << 7) + 64 + lane];                                    \
        A0 += (float)w0[0] * x0.x; A1 += (float)w0[1] * x0.y;                   \
        A2 += (float)w0[2] * x0.z; A3 += (float)w0[3] * x0.w;                   \
        A0 += (float)w0[4] * x1.x; A1 += (float)w0[5] * x1.y;                   \
        A2 += (float)w0[6] * x1.z; A3 += (float)w0[7] * x1.w;                   \
        A0 += (float)w1[0] * x2.x; A1 += (float)w1[1] * x2.y;                   \
        A2 += (float)w1[2] * x2.z; A3 += (float)w1[3] * x2.w;                   \
        A0 += (float)w1[4] * x3.x; A1 += (float)w1[5] * x3.y;                   \
        A2 += (float)w1[6] * x3.z; A3 += (float)w1[7] * x3.w;                   \
    }

// conv: one 64-lane wave per TWO out rows (p, p+1). lanes = 32 f x 2 c-halves.
__global__ void __launch_bounds__(1024, 8)
conv_k(const int* __restrict__ opos, const int* __restrict__ dtable,
       const float* __restrict__ featd, const float* __restrict__ W,
       float* __restrict__ out, int M, int CH) {
    __shared__ _Float16 wlds16[28 * 1024];          // tap 27 = zeros
    __shared__ int srec[16][2][28];

    for (int i = threadIdx.x; i < 28 * 1024; i += blockDim.x) {
        int k = i >> 10, c = (i >> 5) & 31, f = i & 31;
        int j = (c >> 3) & 1, chh = c >> 4, e = c & 7;
        wlds16[((((k << 1) | j) << 1 | chh) << 8) | (f << 3) | e] =
            (i < 27 * 1024) ? (_Float16)W[i] : (_Float16)0.0f;
    }
    __syncthreads();

    const int lane  = threadIdx.x & 63;
    const int f     = lane & 31;
    const int ch    = lane >> 5;            // c-half AND probe/store row half
    const int plane = lane & 31;            // probe lane within half
    const int wslot = threadIdx.x >> 6;
    int (*sr)[28] = srec[wslot];

    // tap offsets for probe lanes (plane 0..26)
    const int dx = plane / 9, dy = (plane / 3) % 3, dz = plane % 3;

    // block-contiguous q chunk, XCD-swizzled; waves cover 32 rows per step
    const int swz  = ((blockIdx.x & 7) << 6) | (blockIdx.x >> 3);
    const int q0   = swz * CH;
    const int qend = min(q0 + CH, M);

    const half8* wp = (const half8*)wlds16;

    // probe lambda: this lane probes its half's row (row = p + ch)
    auto probe = [&](int row) -> int {
        int pv = -1;
        if (plane < 27 && row < qend) {
            int x = opos[3 * row] + dx, y = opos[3 * row + 1] + dy,
                z = opos[3 * row + 2] + dz;
            if (((x | y | z) & ~127) == 0) pv = dtable[(x << 14) | (y << 7) | z];
        }
        return pv;
    };

    int p  = q0 + (wslot << 1);
    int pv = probe(p + ch);

    while (p < qend) {
        int pn  = p + 32;
        int pvn = probe(pn + ch);            // probe-ahead: next pair's loads in flight

        // pad both rows' slots with the dummy record, then compact real ones
        if (plane < 28) sr[ch][plane] = DUMMY_REC;
        unsigned long long m = __ballot(pv >= 0);
        unsigned mlo = (unsigned)m, mhi = (unsigned)(m >> 32);
        int cnt0 = __popc(mlo), cnt1 = __popc(mhi);
        if (pv >= 0) {
            unsigned mh = ch ? mhi : mlo;
            sr[ch][__popc(mh & ((1u << plane) - 1))] = pv | (plane << 18);
        }

        float a00 = 0.f, a01 = 0.f, a02 = 0.f, a03 = 0.f;   // row p
        float a10 = 0.f, a11 = 0.f, a12 = 0.f, a13 = 0.f;   // row p+1
        int mx = (cnt0 > cnt1) ? cnt0 : cnt1;
        for (int r = 0; r < mx; ++r) {       // BRANCHLESS: dummies beyond cnt
            RECBODY(sr[0], r, a00, a01, a02, a03);
            RECBODY(sr[1], r, a10, a11, a12, a13);
        }

        float s0 = (a00 + a01) + (a02 + a03);
        s0 += __shfl_xor(s0, 32);
        float s1 = (a10 + a11) + (a12 + a13);
        s1 += __shfl_xor(s1, 32);
        int row = p + ch;
        if (row < qend) out[(row << 5) + f] = ch ? s1 : s0;  // both halves store

        p = pn; pv = pvn;
    }
}

extern "C" void kernel_launch(void* const* d_in, const int* in_sizes, int n_in,
                              void* d_out, int out_size, void* d_ws, size_t ws_size,
                              hipStream_t stream) {
    const float* features = (const float*)d_in[0];
    const int* in_pos     = (const int*)d_in[1];
    const int* out_pos    = (const int*)d_in[2];
    const float* W        = (const float*)d_in[3];
    float* out            = (float*)d_out;

    const int N = in_sizes[1] / 3;
    const int M = in_sizes[2] / 3;

    char* p = (char*)d_ws;
    int* itable    = (int*)p;   p += (size_t)CELLS * 4;
    int* dtable    = (int*)p;   p += (size_t)CELLS * 4;
    int* ownerof   = (int*)p;   p += (size_t)N * 4;
    int* blockcnt  = (int*)p;   p += 2048 * 4;
    int* blockbase = (int*)p;   p += 2048 * 4;
    int* totalbuf  = (int*)p;   p += 16;
    float* featd   = (float*)p; p += (size_t)N * 32 * 4;

    hipMemsetAsync(itable, 0xFF, (size_t)CELLS * 4, stream);

    claim_k <<<(N + 255) / 256, 256, 0, stream>>>(in_pos, itable, N);
    count_k <<<CELLS / 1024, 1024, 0, stream>>>(itable, blockcnt);
    scan_k  <<<1, 1024, 0, stream>>>(blockcnt, blockbase, totalbuf);
    assign_k<<<CELLS / 1024, 1024, 0, stream>>>(itable, blockbase, dtable, ownerof);
    copy_k  <<<(N * 32 + 255) / 256, 256, 0, stream>>>(ownerof, features, featd, totalbuf, N);
    dup_k   <<<(N * 32 + 255) / 256, 256, 0, stream>>>(in_pos, itable, dtable, features, featd, N);

    const int CH = (M + 511) / 512;
    conv_k  <<<512, 1024, 0, stream>>>(out_pos, dtable, featd, W, out, M, CH);
}